// Round 14
// baseline (153.298 us; speedup 1.0000x reference)
//
#include <hip/hip_runtime.h>
#include <math.h>

#define DEV __device__ __forceinline__

namespace {

struct C2 { float x, y; };

// ---------------- workspace layout (float offsets) ----------------
constexpr size_t OFF_CS   = 0;        // 1024 states * 80 gates * 2 (cos,sin)
constexpr size_t OFF_NRM  = 163988;
constexpr size_t OFF_MONO = 164096;   // 32*1024*float2
constexpr size_t OFF_ACC  = 229632;
constexpr size_t OFF_ST   = 295168;   // 1024*1024*float2
constexpr size_t OFF_H    = 2393280;  // 32*512

// ---------------- lane-xor: uniform __shfl_xor (ds_bpermute) ----------------
// R5-cohort evidence: uniform bpermute evolve profiled <38.7us; the R8+
// DPP/ds_swizzle mix cohort all ~50us. Uniform pipe -> batched lgkmcnt waits.
template<int LM>
DEV float lxor(float x) { return __shfl_xor(x, LM, 64); }

// ---------------- gate primitives (16 regs, full state per wave) ----------
// amplitude index i = (reg<<6) | lane ; wire w lives at bit position P = 9-w.

template<int P>
DEV void ry_gate(C2 v[16], int lane, float c, float s) {
  if constexpr (P >= 6) {
    constexpr int rm = 1 << (P - 6);
#pragma unroll
    for (int r = 0; r < 16; ++r) {
      if ((r & rm) == 0) {
        C2 a = v[r], b = v[r | rm];
        v[r].x      = fmaf(c, a.x, -s * b.x);
        v[r].y      = fmaf(c, a.y, -s * b.y);
        v[r | rm].x = fmaf(s, a.x,  c * b.x);
        v[r | rm].y = fmaf(s, a.y,  c * b.y);
      }
    }
  } else {
    constexpr int lm = 1 << P;
    float sg = (lane & lm) ? s : -s;
#pragma unroll
    for (int r = 0; r < 16; ++r) {
      float px = lxor<lm>(v[r].x);
      float py = lxor<lm>(v[r].y);
      v[r].x = fmaf(c, v[r].x, sg * px);
      v[r].y = fmaf(c, v[r].y, sg * py);
    }
  }
}

template<int PC, int PT>
DEV void crx_gate(C2 v[16], int lane, float c, float s) {
  if constexpr (PT >= 6) {
    constexpr int tm = 1 << (PT - 6);
#pragma unroll
    for (int r = 0; r < 16; ++r) {
      if ((r & tm) == 0) {
        if constexpr (PC >= 6) {
          constexpr int cm = 1 << (PC - 6);
          if ((r & cm) != 0) {
            C2 a = v[r], b = v[r | tm];
            v[r].x      = fmaf(c, a.x,  s * b.y);
            v[r].y      = fmaf(c, a.y, -s * b.x);
            v[r | tm].x = fmaf(c, b.x,  s * a.y);
            v[r | tm].y = fmaf(c, b.y, -s * a.x);
          }
        } else {
          constexpr int cl = 1 << PC;
          bool ct = (lane & cl) != 0;
          C2 a = v[r], b = v[r | tm];
          float nax = fmaf(c, a.x,  s * b.y);
          float nay = fmaf(c, a.y, -s * b.x);
          float nbx = fmaf(c, b.x,  s * a.y);
          float nby = fmaf(c, b.y, -s * a.x);
          v[r].x      = ct ? nax : a.x;
          v[r].y      = ct ? nay : a.y;
          v[r | tm].x = ct ? nbx : b.x;
          v[r | tm].y = ct ? nby : b.y;
        }
      }
    }
  } else {
    constexpr int tm = 1 << PT;
#pragma unroll
    for (int r = 0; r < 16; ++r) {
      if constexpr (PC >= 6) {
        constexpr int cm = 1 << (PC - 6);
        if ((r & cm) == 0) continue;
      }
      float px = lxor<tm>(v[r].x);
      float py = lxor<tm>(v[r].y);
      float nx = fmaf(c, v[r].x,  s * py);
      float ny = fmaf(c, v[r].y, -s * px);
      if constexpr (PC >= 6) {
        v[r].x = nx; v[r].y = ny;
      } else {
        constexpr int cl = 1 << PC;
        bool ct = (lane & cl) != 0;
        v[r].x = ct ? nx : v[r].x;
        v[r].y = ct ? ny : v[r].y;
      }
    }
  }
}

#define RYG(w, g)       ry_gate<9-(w)>(v, lane, cs[2*(g)], cs[2*(g)+1])
#define CRXG(cw, tw, g) crx_gate<9-(cw), 9-(tw)>(v, lane, cs[2*(g)], cs[2*(g)+1])

DEV void apply_layer(C2 v[16], int lane, const float* __restrict__ cs) {
  RYG(0,0); RYG(1,1); RYG(2,2); RYG(3,3); RYG(4,4);
  RYG(5,5); RYG(6,6); RYG(7,7); RYG(8,8); RYG(9,9);
  CRXG(9,0,10); CRXG(8,9,11); CRXG(7,8,12); CRXG(6,7,13); CRXG(5,6,14);
  CRXG(4,5,15); CRXG(3,4,16); CRXG(2,3,17); CRXG(1,2,18); CRXG(0,1,19);
  RYG(0,20); RYG(1,21); RYG(2,22); RYG(3,23); RYG(4,24);
  RYG(5,25); RYG(6,26); RYG(7,27); RYG(8,28); RYG(9,29);
  CRXG(9,8,30); CRXG(0,9,31); CRXG(1,0,32); CRXG(2,1,33); CRXG(3,2,34);
  CRXG(4,3,35); CRXG(5,4,36); CRXG(6,5,37); CRXG(7,6,38); CRXG(8,7,39);
}

template<int P>
DEV void measure_wire(const C2 v[16], int lane, float* ev, int w) {
  float x = 0.f, y = 0.f, z = 0.f;
  if constexpr (P >= 6) {
    constexpr int rm = 1 << (P - 6);
#pragma unroll
    for (int r = 0; r < 16; ++r) {
      if ((r & rm) == 0) {
        C2 a = v[r], b = v[r | rm];
        x += a.x*b.x + a.y*b.y;
        y += a.x*b.y - a.y*b.x;
        z += (a.x*a.x + a.y*a.y) - (b.x*b.x + b.y*b.y);
      }
    }
  } else {
    constexpr int lm = 1 << P;
#pragma unroll
    for (int r = 0; r < 16; ++r) {
      float px = lxor<lm>(v[r].x);
      float py = lxor<lm>(v[r].y);
      if ((lane & lm) == 0) {
        C2 a = v[r];
        x += a.x*px + a.y*py;
        y += a.x*py - a.y*px;
        z += (a.x*a.x + a.y*a.y) - (px*px + py*py);
      }
    }
  }
  for (int s = 1; s < 64; s <<= 1) {
    x += __shfl_xor(x, s, 64);
    y += __shfl_xor(y, s, 64);
    z += __shfl_xor(z, s, 64);
  }
  if (lane == 0) {
    ev[w]      = 2.f * x;
    ev[10 + w] = 2.f * y;
    ev[20 + w] = z;
  }
}

DEV void measure_all(const C2 v[16], int lane, float* ev) {
  measure_wire<9>(v, lane, ev, 0);
  measure_wire<8>(v, lane, ev, 1);
  measure_wire<7>(v, lane, ev, 2);
  measure_wire<6>(v, lane, ev, 3);
  measure_wire<5>(v, lane, ev, 4);
  measure_wire<4>(v, lane, ev, 5);
  measure_wire<3>(v, lane, ev, 6);
  measure_wire<2>(v, lane, ev, 7);
  measure_wire<1>(v, lane, ev, 8);
  measure_wire<0>(v, lane, ev, 9);
}

// ---------------- kernels ----------------

// K2: evolve, unsplit (1 wave = 1 state, 16 regs). 256 blocks x 256 thr.
// Body: unroll-1 layer loop over apply_layer (R5 shape, shfl-only lxor).
// K==1 fuses the 4-token angle computation (320 dots over 256 threads).
template<int K>
__global__ __launch_bounds__(256) void k_evolve(float* __restrict__ ws,
    const float* __restrict__ lr, const float* __restrict__ li,
    const int* __restrict__ x, const float* __restrict__ emb,
    const float* __restrict__ w_ang, const float* __restrict__ b_ang) {
  __shared__ float cs_lds[4][160];
  const int tid = threadIdx.x, g = blockIdx.x;
  const int wid = tid >> 6, lane = tid & 63;
  const int state = g * 4 + wid, b = state >> 5, t = state & 31;

  if constexpr (K == 1) {
    __shared__ float e4[4][512];
#pragma unroll
    for (int p = 0; p < 2; ++p) {
      int idx = tid + p * 256;
      int rr = idx >> 7, col = idx & 127;
      int row = x[g * 4 + rr];
      ((float4*)e4[rr])[col] = ((const float4*)(emb + (size_t)row * 512))[col];
    }
    __syncthreads();
#pragma unroll
    for (int p = 0; p < 2; ++p) {
      int d = tid + p * 256;
      if (d < 320) {
        int tl = d / 80, gate = d - tl * 80;
        const float4* wr = (const float4*)(w_ang + (size_t)gate * 512);
        const float4* ep = (const float4*)e4[tl];
        float a = b_ang[gate];
#pragma unroll 4
        for (int j = 0; j < 128; ++j) {
          float4 w4 = wr[j], e = ep[j];
          a = fmaf(w4.x, e.x, a); a = fmaf(w4.y, e.y, a);
          a = fmaf(w4.z, e.z, a); a = fmaf(w4.w, e.w, a);
        }
        float th = 0.5f * a, cv = cosf(th), sv = sinf(th);
        cs_lds[tl][2 * gate]     = cv;
        cs_lds[tl][2 * gate + 1] = sv;
        size_t go = OFF_CS + (size_t)(g * 4 + tl) * 160 + 2 * gate;
        ws[go] = cv; ws[go + 1] = sv;
      }
    }
    __syncthreads();
  } else {
    const float* csg = ws + OFF_CS + (size_t)g * 640;
    for (int i = tid; i < 640; i += 256) ((float*)cs_lds)[i] = csg[i];
    __syncthreads();
  }

  // lcu weight for this token
  float lre_v = 0.f, lim_v = 0.f;
  if (lane < 32) { lre_v = lr[lane]; lim_v = li[lane]; }
  float ab = sqrtf(lre_v * lre_v + lim_v * lim_v);
  for (int s = 1; s < 64; s <<= 1) ab += __shfl_xor(ab, s, 64);
  float invL = 1.f / fmaxf(ab, 1e-12f);
  float wre = __shfl(lre_v, t, 64) * invL;
  float wim = __shfl(lim_v, t, 64) * invL;

  C2 v[16];
  if constexpr (K == 1) {
#pragma unroll
    for (int r = 0; r < 16; ++r) {
      v[r].x = (r == 0 && lane == 0) ? 1.f : 0.f;
      v[r].y = 0.f;
    }
  } else {
    const float2* mono = (const float2*)(ws + OFF_MONO) + (size_t)b * 1024;
#pragma unroll
    for (int r = 0; r < 16; ++r) {
      float2 m = mono[(r << 6) | lane];
      v[r].x = m.x; v[r].y = m.y;
    }
  }

  const float* csw = cs_lds[wid];
#pragma unroll 1
  for (int l = 0; l < 2; ++l)
    apply_layer(v, lane, csw + l * 80);

  float2* st = (float2*)(ws + OFF_ST) + (size_t)state * 1024;
#pragma unroll
  for (int r = 0; r < 16; ++r) {
    st[(r << 6) | lane] = make_float2(wre * v[r].x - wim * v[r].y,
                                      wre * v[r].y + wim * v[r].x);
  }
}

// K3: mono[b] = sum_t st[b,t]; acc accumulation. 128x256. (k = 1 or 2)
__global__ void k_reduce(float* __restrict__ ws, const float* __restrict__ coef, int k) {
  int idx = blockIdx.x * 256 + threadIdx.x;
  int b = idx >> 10, i = idx & 1023;
  const float2* st = (const float2*)(ws + OFF_ST) + (size_t)b * 32768 + i;
  float sx = 0.f, sy = 0.f;
#pragma unroll
  for (int t = 0; t < 32; ++t) {
    float2 vv = st[t * 1024];
    sx += vv.x; sy += vv.y;
  }
  float2* mono = (float2*)(ws + OFF_MONO);
  float2* acc  = (float2*)(ws + OFF_ACC);
  float ck = coef[k];
  if (k == 1) {
    float e0 = (i == 0) ? coef[0] : 0.f;
    acc[idx] = make_float2(fmaf(ck, sx, e0), ck * sy);
    mono[idx] = make_float2(sx, sy);
  } else {
    float2 a = acc[idx];
    a.x = fmaf(ck, sx, a.x);
    a.y = fmaf(ck, sy, a.y);
    acc[idx] = a;
    mono[idx] = make_float2(sx, sy);
  }
}

// K5: fused k=3 reduce + final circuit + measure + mlp1. 32 blocks x 256.
__global__ __launch_bounds__(256) void k_final(float* __restrict__ ws,
                                               const float* __restrict__ coef,
                                               const float* __restrict__ qff,
                                               const float* __restrict__ w1,
                                               const float* __restrict__ b1) {
  __shared__ float qff_lds[80];
  __shared__ float2 sv[1024];
  __shared__ float ev_lds[30];
  int tid = threadIdx.x;
  int b = blockIdx.x;
  if (tid < 40) {
    float th = 0.5f * qff[tid];
    qff_lds[2 * tid]     = cosf(th);
    qff_lds[2 * tid + 1] = sinf(th);
  }
  float den = fabsf(coef[0]) + fabsf(coef[1]) + fabsf(coef[2]) + fabsf(coef[3]);
  float invd = 1.f / den;
  float c3 = coef[3];
  const float2* stb  = (const float2*)(ws + OFF_ST) + (size_t)b * 32768;
  const float2* accb = (const float2*)(ws + OFF_ACC) + (size_t)b * 1024;
#pragma unroll
  for (int q = 0; q < 4; ++q) {
    int i = tid + q * 256;
    float sx = 0.f, sy = 0.f;
#pragma unroll
    for (int t = 0; t < 32; ++t) {
      float2 vv = stb[t * 1024 + i];
      sx += vv.x; sy += vv.y;
    }
    float2 a = accb[i];
    sv[i] = make_float2(fmaf(c3, sx, a.x) * invd, fmaf(c3, sy, a.y) * invd);
  }
  __syncthreads();
  if (tid < 64) {
    int lane = tid;
    C2 v[16];
    float ssum = 0.f;
#pragma unroll
    for (int r = 0; r < 16; ++r) {
      float2 m = sv[(r << 6) | lane];
      v[r].x = m.x; v[r].y = m.y;
      ssum += v[r].x * v[r].x + v[r].y * v[r].y;
    }
    for (int s = 1; s < 64; s <<= 1) ssum += __shfl_xor(ssum, s, 64);
    float nrm = sqrtf(ssum);
    if (lane == 0) ws[OFF_NRM + b] = nrm;
    float sc = 1.f / fmaxf(nrm, 1e-12f);
#pragma unroll
    for (int r = 0; r < 16; ++r) { v[r].x *= sc; v[r].y *= sc; }
    apply_layer(v, lane, qff_lds);
    measure_all(v, lane, ev_lds);
  }
  __syncthreads();
#pragma unroll
  for (int jj = 0; jj < 2; ++jj) {
    int j = tid + jj * 256;
    const float* wr = w1 + (size_t)j * 30;
    float a = b1[j];
#pragma unroll
    for (int q = 0; q < 30; ++q) a = fmaf(ev_lds[q], wr[q], a);
    ws[OFF_H + b * 512 + j] = fmaxf(a, 0.f);
  }
}

// K7: logits = h @ w2.T + b2.  M=32, N=32000, K=512. (+ mean(norm) by block 0)
__global__ __launch_bounds__(256) void k_logits(const float* __restrict__ ws,
                                                const float* __restrict__ w2,
                                                const float* __restrict__ b2,
                                                float* __restrict__ out) {
  __shared__ float4 hT[4096];
  int tid = threadIdx.x;
  if (blockIdx.x == 0 && tid == 0) {
    float s = 0.f;
    for (int i = 0; i < 32; ++i) s += ws[OFF_NRM + i];
    out[32000u * 32u] = s * (1.f / 32.f);
  }
  const float4* hg = (const float4*)(ws + OFF_H);
#pragma unroll
  for (int p = 0; p < 16; ++p) {
    int idx = tid + p * 256;
    int m = idx >> 7, kf4 = idx & 127;
    hT[m * 128 + (kf4 ^ (m >> 3))] = hg[idx];
  }
  __syncthreads();

  int wv = tid >> 6, lane = tid & 63;
  int mg = lane & 3, nl = lane >> 2;
  int nbase = blockIdx.x * 64;
  float acc[4][8];
#pragma unroll
  for (int j = 0; j < 4; ++j)
#pragma unroll
    for (int mi = 0; mi < 8; ++mi) acc[j][mi] = 0.f;

  const float* wbase = w2 + (size_t)(nbase + nl * 4) * 512 + wv * 128;
  int kqb = wv * 32;
#pragma unroll 2
  for (int kf4 = 0; kf4 < 32; ++kf4) {
    int kcol = kqb + kf4;
    float4 h4[8];
#pragma unroll
    for (int mi = 0; mi < 8; ++mi) {
      int m = mg * 8 + mi;
      h4[mi] = hT[m * 128 + (kcol ^ mg)];
    }
#pragma unroll
    for (int j = 0; j < 4; ++j) {
      float4 w4 = *(const float4*)(wbase + (size_t)j * 512 + kf4 * 4);
#pragma unroll
      for (int mi = 0; mi < 8; ++mi) {
        acc[j][mi] = fmaf(w4.x, h4[mi].x, acc[j][mi]);
        acc[j][mi] = fmaf(w4.y, h4[mi].y, acc[j][mi]);
        acc[j][mi] = fmaf(w4.z, h4[mi].z, acc[j][mi]);
        acc[j][mi] = fmaf(w4.w, h4[mi].w, acc[j][mi]);
      }
    }
  }

  __syncthreads();
#pragma unroll
  for (int mi = 0; mi < 8; ++mi) {
    hT[wv * 512 + lane * 8 + (mi ^ (lane & 7))] =
        make_float4(acc[0][mi], acc[1][mi], acc[2][mi], acc[3][mi]);
  }
  __syncthreads();
  {
    int lane2 = tid & 63, grp = tid >> 6;
    int mg2 = lane2 & 3, nl2 = lane2 >> 2;
#pragma unroll
    for (int jj = 0; jj < 2; ++jj) {
      int mi2 = grp * 2 + jj;
      float4 s0 = hT[0 * 512 + lane2 * 8 + (mi2 ^ (lane2 & 7))];
      float4 s1 = hT[1 * 512 + lane2 * 8 + (mi2 ^ (lane2 & 7))];
      float4 s2 = hT[2 * 512 + lane2 * 8 + (mi2 ^ (lane2 & 7))];
      float4 s3 = hT[3 * 512 + lane2 * 8 + (mi2 ^ (lane2 & 7))];
      float sx = s0.x + s1.x + s2.x + s3.x;
      float sy = s0.y + s1.y + s2.y + s3.y;
      float sz = s0.z + s1.z + s2.z + s3.z;
      float sw = s0.w + s1.w + s2.w + s3.w;
      int m = mg2 * 8 + mi2;
      int col = nbase + nl2 * 4;
      float4 b2v = *(const float4*)(b2 + col);
      float4 res = make_float4(sx + b2v.x, sy + b2v.y, sz + b2v.z, sw + b2v.w);
      *(float4*)(out + (size_t)m * 32000 + col) = res;
    }
  }
}

}  // namespace

extern "C" void kernel_launch(void* const* d_in, const int* in_sizes, int n_in,
                              void* d_out, int out_size, void* d_ws, size_t ws_size,
                              hipStream_t stream) {
  (void)in_sizes; (void)n_in; (void)out_size; (void)ws_size;
  const int*   x    = (const int*)d_in[0];
  const float* emb  = (const float*)d_in[1];
  const float* wang = (const float*)d_in[2];
  const float* bang = (const float*)d_in[3];
  const float* coef = (const float*)d_in[4];
  const float* lre  = (const float*)d_in[5];
  const float* lim  = (const float*)d_in[6];
  const float* qff  = (const float*)d_in[7];
  const float* w1   = (const float*)d_in[8];
  const float* b1   = (const float*)d_in[9];
  const float* w2   = (const float*)d_in[10];
  const float* b2   = (const float*)d_in[11];
  float* out = (float*)d_out;
  float* ws  = (float*)d_ws;

  hipLaunchKernelGGL(k_evolve<1>, dim3(256), dim3(256), 0, stream,
                     ws, lre, lim, x, emb, wang, bang);
  hipLaunchKernelGGL(k_reduce, dim3(128), dim3(256), 0, stream, ws, coef, 1);
  hipLaunchKernelGGL(k_evolve<2>, dim3(256), dim3(256), 0, stream,
                     ws, lre, lim, x, emb, wang, bang);
  hipLaunchKernelGGL(k_reduce, dim3(128), dim3(256), 0, stream, ws, coef, 2);
  hipLaunchKernelGGL(k_evolve<3>, dim3(256), dim3(256), 0, stream,
                     ws, lre, lim, x, emb, wang, bang);
  hipLaunchKernelGGL(k_final,  dim3(32),  dim3(256), 0, stream, ws, coef, qff, w1, b1);
  hipLaunchKernelGGL(k_logits, dim3(500), dim3(256), 0, stream, ws, w2, b2, out);
}

// Round 15
// 139.379 us; speedup vs baseline: 1.0999x; 1.0999x over previous
//
#include <hip/hip_runtime.h>
#include <math.h>

#define DEV __device__ __forceinline__

namespace {

struct C2 { float x, y; };

// ---------------- workspace layout (float offsets) ----------------
constexpr size_t OFF_CS   = 0;        // 1024 states * 80 gates * 2 (cos,sin)
constexpr size_t OFF_NRM  = 163988;
constexpr size_t OFF_MONO = 164096;   // 32*1024*float2
constexpr size_t OFF_ACC  = 229632;
constexpr size_t OFF_ST   = 295168;   // 1024*1024*float2
constexpr size_t OFF_H    = 2393280;  // 32*512

// ---------------- fast lane-xor: DPP (xor1/2/8), ds_swizzle (4/16), shfl (32)
template<int LM>
DEV float lxor(float x) {
  if constexpr (LM == 1) {
    return __int_as_float(__builtin_amdgcn_update_dpp(
        __float_as_int(x), __float_as_int(x), 0xB1, 0xF, 0xF, false));
  } else if constexpr (LM == 2) {
    return __int_as_float(__builtin_amdgcn_update_dpp(
        __float_as_int(x), __float_as_int(x), 0x4E, 0xF, 0xF, false));
  } else if constexpr (LM == 8) {
    // row_ror:8 within 16-lane rows: (lane+8)&15 == lane^8
    return __int_as_float(__builtin_amdgcn_update_dpp(
        __float_as_int(x), __float_as_int(x), 0x128, 0xF, 0xF, false));
  } else if constexpr (LM == 4 || LM == 16) {
    return __int_as_float(__builtin_amdgcn_ds_swizzle(
        __float_as_int(x), (LM << 10) | 0x1F));
  } else {
    return __shfl_xor(x, LM, 64);
  }
}

// ---------------- gate primitives (16 regs, full state per wave) ----------
// amplitude index i = (reg<<6) | lane ; wire w lives at bit position P = 9-w.

template<int P>
DEV void ry_gate(C2 v[16], int lane, float c, float s) {
  if constexpr (P >= 6) {
    constexpr int rm = 1 << (P - 6);
#pragma unroll
    for (int r = 0; r < 16; ++r) {
      if ((r & rm) == 0) {
        C2 a = v[r], b = v[r | rm];
        v[r].x      = fmaf(c, a.x, -s * b.x);
        v[r].y      = fmaf(c, a.y, -s * b.y);
        v[r | rm].x = fmaf(s, a.x,  c * b.x);
        v[r | rm].y = fmaf(s, a.y,  c * b.y);
      }
    }
  } else {
    constexpr int lm = 1 << P;
    float sg = (lane & lm) ? s : -s;
#pragma unroll
    for (int r = 0; r < 16; ++r) {
      float px = lxor<lm>(v[r].x);
      float py = lxor<lm>(v[r].y);
      v[r].x = fmaf(c, v[r].x, sg * px);
      v[r].y = fmaf(c, v[r].y, sg * py);
    }
  }
}

template<int PC, int PT>
DEV void crx_gate(C2 v[16], int lane, float c, float s) {
  if constexpr (PT >= 6) {
    constexpr int tm = 1 << (PT - 6);
#pragma unroll
    for (int r = 0; r < 16; ++r) {
      if ((r & tm) == 0) {
        if constexpr (PC >= 6) {
          constexpr int cm = 1 << (PC - 6);
          if ((r & cm) != 0) {
            C2 a = v[r], b = v[r | tm];
            v[r].x      = fmaf(c, a.x,  s * b.y);
            v[r].y      = fmaf(c, a.y, -s * b.x);
            v[r | tm].x = fmaf(c, b.x,  s * a.y);
            v[r | tm].y = fmaf(c, b.y, -s * a.x);
          }
        } else {
          constexpr int cl = 1 << PC;
          bool ct = (lane & cl) != 0;
          C2 a = v[r], b = v[r | tm];
          float nax = fmaf(c, a.x,  s * b.y);
          float nay = fmaf(c, a.y, -s * b.x);
          float nbx = fmaf(c, b.x,  s * a.y);
          float nby = fmaf(c, b.y, -s * a.x);
          v[r].x      = ct ? nax : a.x;
          v[r].y      = ct ? nay : a.y;
          v[r | tm].x = ct ? nbx : b.x;
          v[r | tm].y = ct ? nby : b.y;
        }
      }
    }
  } else {
    constexpr int tm = 1 << PT;
#pragma unroll
    for (int r = 0; r < 16; ++r) {
      if constexpr (PC >= 6) {
        constexpr int cm = 1 << (PC - 6);
        if ((r & cm) == 0) continue;
      }
      float px = lxor<tm>(v[r].x);
      float py = lxor<tm>(v[r].y);
      float nx = fmaf(c, v[r].x,  s * py);
      float ny = fmaf(c, v[r].y, -s * px);
      if constexpr (PC >= 6) {
        v[r].x = nx; v[r].y = ny;
      } else {
        constexpr int cl = 1 << PC;
        bool ct = (lane & cl) != 0;
        v[r].x = ct ? nx : v[r].x;
        v[r].y = ct ? ny : v[r].y;
      }
    }
  }
}

// ---------------- gate blocks (each emitted ONCE in the evolve loop) -------
DEV void ry_block(C2 v[16], int lane, const float* __restrict__ cs) {
  ry_gate<9>(v, lane, cs[0],  cs[1]);
  ry_gate<8>(v, lane, cs[2],  cs[3]);
  ry_gate<7>(v, lane, cs[4],  cs[5]);
  ry_gate<6>(v, lane, cs[6],  cs[7]);
  ry_gate<5>(v, lane, cs[8],  cs[9]);
  ry_gate<4>(v, lane, cs[10], cs[11]);
  ry_gate<3>(v, lane, cs[12], cs[13]);
  ry_gate<2>(v, lane, cs[14], cs[15]);
  ry_gate<1>(v, lane, cs[16], cs[17]);
  ry_gate<0>(v, lane, cs[18], cs[19]);
}

DEV void crx_down(C2 v[16], int lane, const float* __restrict__ cs) {
  crx_gate<0,9>(v, lane, cs[0],  cs[1]);
  crx_gate<1,0>(v, lane, cs[2],  cs[3]);
  crx_gate<2,1>(v, lane, cs[4],  cs[5]);
  crx_gate<3,2>(v, lane, cs[6],  cs[7]);
  crx_gate<4,3>(v, lane, cs[8],  cs[9]);
  crx_gate<5,4>(v, lane, cs[10], cs[11]);
  crx_gate<6,5>(v, lane, cs[12], cs[13]);
  crx_gate<7,6>(v, lane, cs[14], cs[15]);
  crx_gate<8,7>(v, lane, cs[16], cs[17]);
  crx_gate<9,8>(v, lane, cs[18], cs[19]);
}

DEV void crx_up(C2 v[16], int lane, const float* __restrict__ cs) {
  crx_gate<0,1>(v, lane, cs[0],  cs[1]);
  crx_gate<9,0>(v, lane, cs[2],  cs[3]);
  crx_gate<8,9>(v, lane, cs[4],  cs[5]);
  crx_gate<7,8>(v, lane, cs[6],  cs[7]);
  crx_gate<6,7>(v, lane, cs[8],  cs[9]);
  crx_gate<5,6>(v, lane, cs[10], cs[11]);
  crx_gate<4,5>(v, lane, cs[12], cs[13]);
  crx_gate<3,4>(v, lane, cs[14], cs[15]);
  crx_gate<2,3>(v, lane, cs[16], cs[17]);
  crx_gate<1,2>(v, lane, cs[18], cs[19]);
}

// full layer (used by k_final only; k_evolve uses the 8-phase loop)
DEV void apply_layer(C2 v[16], int lane, const float* __restrict__ cs) {
  ry_block(v, lane, cs);
  crx_down(v, lane, cs + 20);
  ry_block(v, lane, cs + 40);
  crx_up(v, lane, cs + 60);
}

template<int P>
DEV void measure_wire(const C2 v[16], int lane, float* ev, int w) {
  float x = 0.f, y = 0.f, z = 0.f;
  if constexpr (P >= 6) {
    constexpr int rm = 1 << (P - 6);
#pragma unroll
    for (int r = 0; r < 16; ++r) {
      if ((r & rm) == 0) {
        C2 a = v[r], b = v[r | rm];
        x += a.x*b.x + a.y*b.y;
        y += a.x*b.y - a.y*b.x;
        z += (a.x*a.x + a.y*a.y) - (b.x*b.x + b.y*b.y);
      }
    }
  } else {
    constexpr int lm = 1 << P;
#pragma unroll
    for (int r = 0; r < 16; ++r) {
      float px = lxor<lm>(v[r].x);
      float py = lxor<lm>(v[r].y);
      if ((lane & lm) == 0) {
        C2 a = v[r];
        x += a.x*px + a.y*py;
        y += a.x*py - a.y*px;
        z += (a.x*a.x + a.y*a.y) - (px*px + py*py);
      }
    }
  }
  for (int s = 1; s < 64; s <<= 1) {
    x += __shfl_xor(x, s, 64);
    y += __shfl_xor(y, s, 64);
    z += __shfl_xor(z, s, 64);
  }
  if (lane == 0) {
    ev[w]      = 2.f * x;
    ev[10 + w] = 2.f * y;
    ev[20 + w] = z;
  }
}

DEV void measure_all(const C2 v[16], int lane, float* ev) {
  measure_wire<9>(v, lane, ev, 0);
  measure_wire<8>(v, lane, ev, 1);
  measure_wire<7>(v, lane, ev, 2);
  measure_wire<6>(v, lane, ev, 3);
  measure_wire<5>(v, lane, ev, 4);
  measure_wire<4>(v, lane, ev, 5);
  measure_wire<3>(v, lane, ev, 6);
  measure_wire<2>(v, lane, ev, 7);
  measure_wire<1>(v, lane, ev, 8);
  measure_wire<0>(v, lane, ev, 9);
}

// ---------------- kernels ----------------

// K2: evolve, unsplit (1 wave = 1 state, 16 regs). 256 blocks x 256 thr.
// Gate application via an 8-phase uniform-switch loop so each gate-block
// body is emitted ONCE (~20KB total) and fits the 32KB I-cache.
// K==1 fuses the 4-token angle computation (320 dots over 256 threads).
template<int K>
__global__ __launch_bounds__(256) void k_evolve(float* __restrict__ ws,
    const float* __restrict__ lr, const float* __restrict__ li,
    const int* __restrict__ x, const float* __restrict__ emb,
    const float* __restrict__ w_ang, const float* __restrict__ b_ang) {
  __shared__ float cs_lds[4][160];
  const int tid = threadIdx.x, g = blockIdx.x;
  const int wid = tid >> 6, lane = tid & 63;
  const int state = g * 4 + wid, b = state >> 5, t = state & 31;

  if constexpr (K == 1) {
    __shared__ float e4[4][512];
#pragma unroll
    for (int p = 0; p < 2; ++p) {
      int idx = tid + p * 256;
      int rr = idx >> 7, col = idx & 127;
      int row = x[g * 4 + rr];
      ((float4*)e4[rr])[col] = ((const float4*)(emb + (size_t)row * 512))[col];
    }
    __syncthreads();
#pragma unroll
    for (int p = 0; p < 2; ++p) {
      int d = tid + p * 256;
      if (d < 320) {
        int tl = d / 80, gate = d - tl * 80;
        const float4* wr = (const float4*)(w_ang + (size_t)gate * 512);
        const float4* ep = (const float4*)e4[tl];
        float a = b_ang[gate];
#pragma unroll 4
        for (int j = 0; j < 128; ++j) {
          float4 w4 = wr[j], e = ep[j];
          a = fmaf(w4.x, e.x, a); a = fmaf(w4.y, e.y, a);
          a = fmaf(w4.z, e.z, a); a = fmaf(w4.w, e.w, a);
        }
        float th = 0.5f * a, cv = cosf(th), sv = sinf(th);
        cs_lds[tl][2 * gate]     = cv;
        cs_lds[tl][2 * gate + 1] = sv;
        size_t go = OFF_CS + (size_t)(g * 4 + tl) * 160 + 2 * gate;
        ws[go] = cv; ws[go + 1] = sv;
      }
    }
    __syncthreads();
  } else {
    const float* csg = ws + OFF_CS + (size_t)g * 640;
    for (int i = tid; i < 640; i += 256) ((float*)cs_lds)[i] = csg[i];
    __syncthreads();
  }

  // lcu weight for this token
  float lre_v = 0.f, lim_v = 0.f;
  if (lane < 32) { lre_v = lr[lane]; lim_v = li[lane]; }
  float ab = sqrtf(lre_v * lre_v + lim_v * lim_v);
  for (int s = 1; s < 64; s <<= 1) ab += __shfl_xor(ab, s, 64);
  float invL = 1.f / fmaxf(ab, 1e-12f);
  float wre = __shfl(lre_v, t, 64) * invL;
  float wim = __shfl(lim_v, t, 64) * invL;

  C2 v[16];
  if constexpr (K == 1) {
#pragma unroll
    for (int r = 0; r < 16; ++r) {
      v[r].x = (r == 0 && lane == 0) ? 1.f : 0.f;
      v[r].y = 0.f;
    }
  } else {
    const float2* mono = (const float2*)(ws + OFF_MONO) + (size_t)b * 1024;
#pragma unroll
    for (int r = 0; r < 16; ++r) {
      float2 m = mono[(r << 6) | lane];
      v[r].x = m.x; v[r].y = m.y;
    }
  }

  // ---- 8-phase gate loop: {RY, CRXdown, RY, CRXup} x 2 layers ----
  const float* csw = cs_lds[wid];
#pragma unroll 1
  for (int ph = 0; ph < 8; ++ph) {
    const int l = ph >> 2, sub = ph & 3;
    const float* c = csw + l * 80 + sub * 20;
    if (sub == 1)      crx_down(v, lane, c);
    else if (sub == 3) crx_up(v, lane, c);
    else               ry_block(v, lane, c);
  }

  float2* st = (float2*)(ws + OFF_ST) + (size_t)state * 1024;
#pragma unroll
  for (int r = 0; r < 16; ++r) {
    st[(r << 6) | lane] = make_float2(wre * v[r].x - wim * v[r].y,
                                      wre * v[r].y + wim * v[r].x);
  }
}

// K3: mono[b] = sum_t st[b,t]; acc accumulation. 128x256. (k = 1 or 2)
__global__ void k_reduce(float* __restrict__ ws, const float* __restrict__ coef, int k) {
  int idx = blockIdx.x * 256 + threadIdx.x;
  int b = idx >> 10, i = idx & 1023;
  const float2* st = (const float2*)(ws + OFF_ST) + (size_t)b * 32768 + i;
  float sx = 0.f, sy = 0.f;
#pragma unroll
  for (int t = 0; t < 32; ++t) {
    float2 vv = st[t * 1024];
    sx += vv.x; sy += vv.y;
  }
  float2* mono = (float2*)(ws + OFF_MONO);
  float2* acc  = (float2*)(ws + OFF_ACC);
  float ck = coef[k];
  if (k == 1) {
    float e0 = (i == 0) ? coef[0] : 0.f;
    acc[idx] = make_float2(fmaf(ck, sx, e0), ck * sy);
    mono[idx] = make_float2(sx, sy);
  } else {
    float2 a = acc[idx];
    a.x = fmaf(ck, sx, a.x);
    a.y = fmaf(ck, sy, a.y);
    acc[idx] = a;
    mono[idx] = make_float2(sx, sy);
  }
}

// K5: fused k=3 reduce + final circuit + measure + mlp1. 32 blocks x 256.
__global__ __launch_bounds__(256) void k_final(float* __restrict__ ws,
                                               const float* __restrict__ coef,
                                               const float* __restrict__ qff,
                                               const float* __restrict__ w1,
                                               const float* __restrict__ b1) {
  __shared__ float qff_lds[80];
  __shared__ float2 sv[1024];
  __shared__ float ev_lds[30];
  int tid = threadIdx.x;
  int b = blockIdx.x;
  if (tid < 40) {
    float th = 0.5f * qff[tid];
    qff_lds[2 * tid]     = cosf(th);
    qff_lds[2 * tid + 1] = sinf(th);
  }
  float den = fabsf(coef[0]) + fabsf(coef[1]) + fabsf(coef[2]) + fabsf(coef[3]);
  float invd = 1.f / den;
  float c3 = coef[3];
  const float2* stb  = (const float2*)(ws + OFF_ST) + (size_t)b * 32768;
  const float2* accb = (const float2*)(ws + OFF_ACC) + (size_t)b * 1024;
#pragma unroll
  for (int q = 0; q < 4; ++q) {
    int i = tid + q * 256;
    float sx = 0.f, sy = 0.f;
#pragma unroll
    for (int t = 0; t < 32; ++t) {
      float2 vv = stb[t * 1024 + i];
      sx += vv.x; sy += vv.y;
    }
    float2 a = accb[i];
    sv[i] = make_float2(fmaf(c3, sx, a.x) * invd, fmaf(c3, sy, a.y) * invd);
  }
  __syncthreads();
  if (tid < 64) {
    int lane = tid;
    C2 v[16];
    float ssum = 0.f;
#pragma unroll
    for (int r = 0; r < 16; ++r) {
      float2 m = sv[(r << 6) | lane];
      v[r].x = m.x; v[r].y = m.y;
      ssum += v[r].x * v[r].x + v[r].y * v[r].y;
    }
    for (int s = 1; s < 64; s <<= 1) ssum += __shfl_xor(ssum, s, 64);
    float nrm = sqrtf(ssum);
    if (lane == 0) ws[OFF_NRM + b] = nrm;
    float sc = 1.f / fmaxf(nrm, 1e-12f);
#pragma unroll
    for (int r = 0; r < 16; ++r) { v[r].x *= sc; v[r].y *= sc; }
    apply_layer(v, lane, qff_lds);
    measure_all(v, lane, ev_lds);
  }
  __syncthreads();
#pragma unroll
  for (int jj = 0; jj < 2; ++jj) {
    int j = tid + jj * 256;
    const float* wr = w1 + (size_t)j * 30;
    float a = b1[j];
#pragma unroll
    for (int q = 0; q < 30; ++q) a = fmaf(ev_lds[q], wr[q], a);
    ws[OFF_H + b * 512 + j] = fmaxf(a, 0.f);
  }
}

// K7: logits = h @ w2.T + b2.  M=32, N=32000, K=512. (+ mean(norm) by block 0)
__global__ __launch_bounds__(256) void k_logits(const float* __restrict__ ws,
                                                const float* __restrict__ w2,
                                                const float* __restrict__ b2,
                                                float* __restrict__ out) {
  __shared__ float4 hT[4096];
  int tid = threadIdx.x;
  if (blockIdx.x == 0 && tid == 0) {
    float s = 0.f;
    for (int i = 0; i < 32; ++i) s += ws[OFF_NRM + i];
    out[32000u * 32u] = s * (1.f / 32.f);
  }
  const float4* hg = (const float4*)(ws + OFF_H);
#pragma unroll
  for (int p = 0; p < 16; ++p) {
    int idx = tid + p * 256;
    int m = idx >> 7, kf4 = idx & 127;
    hT[m * 128 + (kf4 ^ (m >> 3))] = hg[idx];
  }
  __syncthreads();

  int wv = tid >> 6, lane = tid & 63;
  int mg = lane & 3, nl = lane >> 2;
  int nbase = blockIdx.x * 64;
  float acc[4][8];
#pragma unroll
  for (int j = 0; j < 4; ++j)
#pragma unroll
    for (int mi = 0; mi < 8; ++mi) acc[j][mi] = 0.f;

  const float* wbase = w2 + (size_t)(nbase + nl * 4) * 512 + wv * 128;
  int kqb = wv * 32;
#pragma unroll 2
  for (int kf4 = 0; kf4 < 32; ++kf4) {
    int kcol = kqb + kf4;
    float4 h4[8];
#pragma unroll
    for (int mi = 0; mi < 8; ++mi) {
      int m = mg * 8 + mi;
      h4[mi] = hT[m * 128 + (kcol ^ mg)];
    }
#pragma unroll
    for (int j = 0; j < 4; ++j) {
      float4 w4 = *(const float4*)(wbase + (size_t)j * 512 + kf4 * 4);
#pragma unroll
      for (int mi = 0; mi < 8; ++mi) {
        acc[j][mi] = fmaf(w4.x, h4[mi].x, acc[j][mi]);
        acc[j][mi] = fmaf(w4.y, h4[mi].y, acc[j][mi]);
        acc[j][mi] = fmaf(w4.z, h4[mi].z, acc[j][mi]);
        acc[j][mi] = fmaf(w4.w, h4[mi].w, acc[j][mi]);
      }
    }
  }

  __syncthreads();
#pragma unroll
  for (int mi = 0; mi < 8; ++mi) {
    hT[wv * 512 + lane * 8 + (mi ^ (lane & 7))] =
        make_float4(acc[0][mi], acc[1][mi], acc[2][mi], acc[3][mi]);
  }
  __syncthreads();
  {
    int lane2 = tid & 63, grp = tid >> 6;
    int mg2 = lane2 & 3, nl2 = lane2 >> 2;
#pragma unroll
    for (int jj = 0; jj < 2; ++jj) {
      int mi2 = grp * 2 + jj;
      float4 s0 = hT[0 * 512 + lane2 * 8 + (mi2 ^ (lane2 & 7))];
      float4 s1 = hT[1 * 512 + lane2 * 8 + (mi2 ^ (lane2 & 7))];
      float4 s2 = hT[2 * 512 + lane2 * 8 + (mi2 ^ (lane2 & 7))];
      float4 s3 = hT[3 * 512 + lane2 * 8 + (mi2 ^ (lane2 & 7))];
      float sx = s0.x + s1.x + s2.x + s3.x;
      float sy = s0.y + s1.y + s2.y + s3.y;
      float sz = s0.z + s1.z + s2.z + s3.z;
      float sw = s0.w + s1.w + s2.w + s3.w;
      int m = mg2 * 8 + mi2;
      int col = nbase + nl2 * 4;
      float4 b2v = *(const float4*)(b2 + col);
      float4 res = make_float4(sx + b2v.x, sy + b2v.y, sz + b2v.z, sw + b2v.w);
      *(float4*)(out + (size_t)m * 32000 + col) = res;
    }
  }
}

}  // namespace

extern "C" void kernel_launch(void* const* d_in, const int* in_sizes, int n_in,
                              void* d_out, int out_size, void* d_ws, size_t ws_size,
                              hipStream_t stream) {
  (void)in_sizes; (void)n_in; (void)out_size; (void)ws_size;
  const int*   x    = (const int*)d_in[0];
  const float* emb  = (const float*)d_in[1];
  const float* wang = (const float*)d_in[2];
  const float* bang = (const float*)d_in[3];
  const float* coef = (const float*)d_in[4];
  const float* lre  = (const float*)d_in[5];
  const float* lim  = (const float*)d_in[6];
  const float* qff  = (const float*)d_in[7];
  const float* w1   = (const float*)d_in[8];
  const float* b1   = (const float*)d_in[9];
  const float* w2   = (const float*)d_in[10];
  const float* b2   = (const float*)d_in[11];
  float* out = (float*)d_out;
  float* ws  = (float*)d_ws;

  hipLaunchKernelGGL(k_evolve<1>, dim3(256), dim3(256), 0, stream,
                     ws, lre, lim, x, emb, wang, bang);
  hipLaunchKernelGGL(k_reduce, dim3(128), dim3(256), 0, stream, ws, coef, 1);
  hipLaunchKernelGGL(k_evolve<2>, dim3(256), dim3(256), 0, stream,
                     ws, lre, lim, x, emb, wang, bang);
  hipLaunchKernelGGL(k_reduce, dim3(128), dim3(256), 0, stream, ws, coef, 2);
  hipLaunchKernelGGL(k_evolve<3>, dim3(256), dim3(256), 0, stream,
                     ws, lre, lim, x, emb, wang, bang);
  hipLaunchKernelGGL(k_final,  dim3(32),  dim3(256), 0, stream, ws, coef, qff, w1, b1);
  hipLaunchKernelGGL(k_logits, dim3(500), dim3(256), 0, stream, ws, w2, b2, out);
}